// Round 12
// baseline (112.606 us; speedup 1.0000x reference)
//
#include <hip/hip_runtime.h>
#include <hip/hip_bf16.h>

// RBF network, MI355X (gfx950). B=131072, D=64, H=512, O=16.
// R12 (from R9 post-mortem): harness ws-poison fill (~43us) dominates the profile;
// kernel itself ~29us. Changes:
//  - 64 rows/wave, grid 512: halves L2 frag traffic per row, 4 independent
//    MFMA chains per wave (ILP), exactly 2 blocks/CU fully resident, no tail.
//  - native float->bf16 casts (compiler emits v_cvt_pk_bf16_f32; manual
//    bit-twiddle f2bf blocked it) in the hot loop.
// Structure unchanged: zero barriers, wave-independent, prep kernel fragments
// centroid/weight/coef into d_ws (86KB, L2-resident).

#define NDIM 64
#define NHID 512
#define NOUT 16
#define LOG2E 1.4426950408889634f

typedef __attribute__((ext_vector_type(8))) short bf16x8;  // 8 bf16 in 4 VGPRs
typedef __attribute__((ext_vector_type(4))) float f32x4;
typedef __attribute__((ext_vector_type(2))) float f32x2;

#if __has_builtin(__builtin_amdgcn_exp2f)
#define EXP2F(x) __builtin_amdgcn_exp2f(x)
#else
#define EXP2F(x) exp2f(x)
#endif

// fp32 -> bf16 RNE, via native conversion (compiler picks cvt_pk where possible)
static __device__ __forceinline__ short f2bf_n(float f) {
    __hip_bfloat16 b = __float2bfloat16(f);
    return *(short*)&b;
}
// bit-exact manual fallback used only in prep (cold)
static __device__ __forceinline__ short f2bf(float f) {
    unsigned int u = __float_as_uint(f);
    unsigned int r = (u + 0x7FFFu + ((u >> 16) & 1u)) >> 16;
    return (short)r;
}

// d_ws layout (bytes)
#define WS_CFRAG 0          // 64 KB: bf16 centroid frags: [(nt*2+kc)*64 + lane]*16B
#define WS_WFRAG 65536      // 16 KB: bf16 weight frags:  [ks*64 + lane]*16B
#define WS_COF   81920      //  4 KB: float2 (a, -a*csq) per h

__global__ __launch_bounds__(64)
void rbf_prep(const float* __restrict__ cen, const float* __restrict__ sig,
              const float* __restrict__ wgt, char* __restrict__ ws)
{
    const int blk = blockIdx.x;
    const int d = threadIdx.x;
    if (blk < NHID) {
        const int h = blk;
        const float v = cen[h * NDIM + d];
        float sq = v * v;
        sq += __shfl_xor(sq, 1);
        sq += __shfl_xor(sq, 2);
        sq += __shfl_xor(sq, 4);
        sq += __shfl_xor(sq, 8);
        sq += __shfl_xor(sq, 16);
        sq += __shfl_xor(sq, 32);
        if (d == 0) {
            float s = sig[h];
            float a = LOG2E / (2.0f * s * s);
            a = fminf(a, 1e30f);                 // sigma==0 guard
            f32x2 cf; cf[0] = a; cf[1] = -a * sq;
            *(f32x2*)(ws + WS_COF + h * 8) = cf;
        }
        // frag position: nt=h>>4, cp=h&15, kc=d>>5, g=(d>>3)&3, j=d&7
        const int nt = h >> 4, cp = h & 15, kc = d >> 5, g = (d >> 3) & 3, j = d & 7;
        const int byte = (((nt * 2 + kc) * 64) + g * 16 + cp) * 16 + j * 2;
        *(short*)(ws + WS_CFRAG + byte) = f2bf(v);
    } else {
        const int ks = blk - NHID;               // 0..15
        const int g = d >> 4, c = d & 15;
        bf16x8 f;
#pragma unroll
        for (int j = 0; j < 8; ++j)
            f[j] = f2bf(wgt[(ks * 32 + g * 8 + j) * NOUT + c]);
        *(bf16x8*)(ws + WS_WFRAG + (ks * 64 + d) * 16) = f;
    }
}

__global__ __launch_bounds__(256, 2)
void rbf_main(const float* __restrict__ x, const float* __restrict__ bias,
              const char* __restrict__ ws, float* __restrict__ out)
{
    // wave-private hid chunk, double-buffered: [wave][buf][m 0..63][kk 0..31 pad 40]
    // row stride 40 shorts = 80B -> 16B-aligned b128 reads at g*8. 40KB total.
    __shared__ __align__(16) short hidb[4][2][64][40];

    const int tid  = threadIdx.x;
    const int w    = tid >> 6;
    const int lane = tid & 63;
    const int g    = lane >> 4;
    const int c    = lane & 15;
    const long r0  = (long)blockIdx.x * 256 + w * 64;

    const bf16x8* cfrag = (const bf16x8*)(ws + WS_CFRAG);
    const bf16x8* wfrag = (const bf16x8*)(ws + WS_WFRAG);
    const char*   cofp  = ws + WS_COF;

    // ---- x A-frags (bf16) + xsq per C-row, 4 groups of 16 rows ----
    bf16x8 A[4][2];
    float xs4[4][4];
#pragma unroll
    for (int mg = 0; mg < 4; ++mg) {
        const float* xr = x + (r0 + mg * 16 + c) * NDIM;
        float sqs = 0.f;
#pragma unroll
        for (int kc = 0; kc < 2; ++kc) {
            f32x4 v0 = *(const f32x4*)(xr + kc * 32 + g * 8);
            f32x4 v1 = *(const f32x4*)(xr + kc * 32 + g * 8 + 4);
            sqs += v0[0]*v0[0] + v0[1]*v0[1] + v0[2]*v0[2] + v0[3]*v0[3];
            sqs += v1[0]*v1[0] + v1[1]*v1[1] + v1[2]*v1[2] + v1[3]*v1[3];
            bf16x8 f;
            f[0]=f2bf_n(v0[0]); f[1]=f2bf_n(v0[1]); f[2]=f2bf_n(v0[2]); f[3]=f2bf_n(v0[3]);
            f[4]=f2bf_n(v1[0]); f[5]=f2bf_n(v1[1]); f[6]=f2bf_n(v1[2]); f[7]=f2bf_n(v1[3]);
            A[mg][kc] = f;
        }
        sqs += __shfl_xor(sqs, 16);   // combine the 4 g-chunks of row (mg, c)
        sqs += __shfl_xor(sqs, 32);
#pragma unroll
        for (int rr = 0; rr < 4; ++rr)
            xs4[mg][rr] = __shfl(sqs, 4 * g + rr);   // xsq of C-layout row 4g+rr
    }

    // ---- main loop: 16 K-chunks of 32 h, zero barriers ----
    f32x4 acc2[4] = {{0.f,0.f,0.f,0.f},{0.f,0.f,0.f,0.f},
                     {0.f,0.f,0.f,0.f},{0.f,0.f,0.f,0.f}};
#pragma unroll
    for (int ks = 0; ks < 16; ++ks) {
#pragma unroll
        for (int t = 0; t < 2; ++t) {
            const int nt = 2 * ks + t;
            const f32x2 cf = *(const f32x2*)(cofp + (nt * 16 + c) * 8);
            const float a = cf[0], nb = cf[1];
            const float A2 = a + a;
            const bf16x8 b0 = cfrag[(nt * 2 + 0) * 64 + lane];
            const bf16x8 b1 = cfrag[(nt * 2 + 1) * 64 + lane];
#pragma unroll
            for (int mg = 0; mg < 4; ++mg) {
                f32x4 z = {0.f, 0.f, 0.f, 0.f};
                f32x4 acc = __builtin_amdgcn_mfma_f32_16x16x32_bf16(A[mg][0], b0, z, 0, 0, 0);
                acc = __builtin_amdgcn_mfma_f32_16x16x32_bf16(A[mg][1], b1, acc, 0, 0, 0);
#pragma unroll
                for (int rr = 0; rr < 4; ++rr) {
                    float nbx = fmaf(-a, xs4[mg][rr], nb);
                    float arg = fmaf(A2, acc[rr], nbx);
                    hidb[w][ks & 1][mg * 16 + 4 * g + rr][t * 16 + c] = f2bf_n(EXP2F(arg));
                }
            }
        }
        // GEMM2 for this 32-h chunk (same-wave LDS ordering; no barrier needed)
        const bf16x8 wf = wfrag[ks * 64 + lane];
#pragma unroll
        for (int mg = 0; mg < 4; ++mg) {
            const bf16x8 a2 = *(const bf16x8*)&hidb[w][ks & 1][c + mg * 16][g * 8];
            acc2[mg] = __builtin_amdgcn_mfma_f32_16x16x32_bf16(a2, wf, acc2[mg], 0, 0, 0);
        }
    }

    // ---- epilogue in registers: bias, row-sum over o (c-lanes), normalize ----
    const float bv = bias[c];
#pragma unroll
    for (int mg = 0; mg < 4; ++mg) {
        f32x4 v, s;
#pragma unroll
        for (int rr = 0; rr < 4; ++rr) { v[rr] = acc2[mg][rr] + bv; s[rr] = v[rr]; }
#pragma unroll
        for (int off = 1; off <= 8; off <<= 1) {
#pragma unroll
            for (int rr = 0; rr < 4; ++rr) s[rr] += __shfl_xor(s[rr], off);
        }
#pragma unroll
        for (int rr = 0; rr < 4; ++rr)
            out[(r0 + mg * 16 + 4 * g + rr) * NOUT + c] = v[rr] / s[rr];
    }
}

extern "C" void kernel_launch(void* const* d_in, const int* in_sizes, int n_in,
                              void* d_out, int out_size, void* d_ws, size_t ws_size,
                              hipStream_t stream) {
    const float* x    = (const float*)d_in[0];
    const float* cen  = (const float*)d_in[1];
    const float* sig  = (const float*)d_in[2];
    const float* wgt  = (const float*)d_in[3];
    const float* bias = (const float*)d_in[4];
    float* out = (float*)d_out;
    (void)in_sizes; (void)n_in; (void)ws_size; (void)out_size;

    char* ws = (char*)d_ws;
    rbf_prep<<<dim3(NHID + 16), dim3(64), 0, stream>>>(cen, sig, wgt, ws);
    rbf_main<<<dim3(512), dim3(256), 0, stream>>>(x, bias, ws, out);
}

// Round 14
// 102.577 us; speedup vs baseline: 1.0978x; 1.0978x over previous
//
#include <hip/hip_runtime.h>
#include <hip/hip_bf16.h>

// RBF network, MI355X (gfx950). B=131072, D=64, H=512, O=16.
// R13 (from R12 post-mortem): R12's 64-rows/wave halved resident waves
// (19% occ) and main regressed to 44.9us with VALUBusy 24% -> latency-stalled.
// Changes:
//  - back to 32 rows/wave, grid 1024 (4 blocks/CU, 16 waves/CU).
//  - explicit 1-chunk register prefetch: chunk ks+1 operands (2 coef, 4 cfrag,
//    1 wfrag = 24 VGPRs) loaded into a named ping-pong set before chunk ks's
//    compute -> load->use distance = one full chunk of MFMA+exp+LDS work.
//    (R12 showed the compiler won't do this itself: VGPR_Count=56.)
// Structure: zero barriers, wave-independent; prep fragments operands into d_ws.

#define NDIM 64
#define NHID 512
#define NOUT 16
#define LOG2E 1.4426950408889634f

typedef __attribute__((ext_vector_type(8))) short bf16x8;  // 8 bf16 in 4 VGPRs
typedef __attribute__((ext_vector_type(4))) float f32x4;
typedef __attribute__((ext_vector_type(2))) float f32x2;

#if __has_builtin(__builtin_amdgcn_exp2f)
#define EXP2F(x) __builtin_amdgcn_exp2f(x)
#else
#define EXP2F(x) exp2f(x)
#endif

// fp32 -> bf16 RNE via native conversion (compiler can pack to v_cvt_pk_bf16_f32)
static __device__ __forceinline__ short f2bf_n(float f) {
    __hip_bfloat16 b = __float2bfloat16(f);
    return *(short*)&b;
}
// bit-exact manual version (cold path / prep)
static __device__ __forceinline__ short f2bf(float f) {
    unsigned int u = __float_as_uint(f);
    unsigned int r = (u + 0x7FFFu + ((u >> 16) & 1u)) >> 16;
    return (short)r;
}

// d_ws layout (bytes)
#define WS_CFRAG 0          // 64 KB: bf16 centroid frags: [(nt*2+kc)*64 + lane]*16B
#define WS_WFRAG 65536      // 16 KB: bf16 weight frags:  [ks*64 + lane]*16B
#define WS_COF   81920      //  4 KB: float2 (a, -a*csq) per h

__global__ __launch_bounds__(64)
void rbf_prep(const float* __restrict__ cen, const float* __restrict__ sig,
              const float* __restrict__ wgt, char* __restrict__ ws)
{
    const int blk = blockIdx.x;
    const int d = threadIdx.x;
    if (blk < NHID) {
        const int h = blk;
        const float v = cen[h * NDIM + d];
        float sq = v * v;
        sq += __shfl_xor(sq, 1);
        sq += __shfl_xor(sq, 2);
        sq += __shfl_xor(sq, 4);
        sq += __shfl_xor(sq, 8);
        sq += __shfl_xor(sq, 16);
        sq += __shfl_xor(sq, 32);
        if (d == 0) {
            float s = sig[h];
            float a = LOG2E / (2.0f * s * s);
            a = fminf(a, 1e30f);                 // sigma==0 guard
            f32x2 cf; cf[0] = a; cf[1] = -a * sq;
            *(f32x2*)(ws + WS_COF + h * 8) = cf;
        }
        // frag position: nt=h>>4, cp=h&15, kc=d>>5, g=(d>>3)&3, j=d&7
        const int nt = h >> 4, cp = h & 15, kc = d >> 5, g = (d >> 3) & 3, j = d & 7;
        const int byte = (((nt * 2 + kc) * 64) + g * 16 + cp) * 16 + j * 2;
        *(short*)(ws + WS_CFRAG + byte) = f2bf(v);
    } else {
        const int ks = blk - NHID;               // 0..15
        const int g = d >> 4, c = d & 15;
        bf16x8 f;
#pragma unroll
        for (int j = 0; j < 8; ++j)
            f[j] = f2bf(wgt[(ks * 32 + g * 8 + j) * NOUT + c]);
        *(bf16x8*)(ws + WS_WFRAG + (ks * 64 + d) * 16) = f;
    }
}

__global__ __launch_bounds__(256, 2)
void rbf_main(const float* __restrict__ x, const float* __restrict__ bias,
              const char* __restrict__ ws, float* __restrict__ out)
{
    // wave-private hid chunk, double-buffered: [wave][buf][m 0..31][kk 0..31 pad 40]
    __shared__ __align__(16) short hidb[4][2][32][40];

    const int tid  = threadIdx.x;
    const int w    = tid >> 6;
    const int lane = tid & 63;
    const int g    = lane >> 4;
    const int c    = lane & 15;
    const long r0  = (long)blockIdx.x * 128 + w * 32;

    const bf16x8* cfrag = (const bf16x8*)(ws + WS_CFRAG);
    const bf16x8* wfrag = (const bf16x8*)(ws + WS_WFRAG);
    const char*   cofp  = ws + WS_COF;

    // ---- x A-frags (bf16) + xsq per C-row ----
    bf16x8 A[2][2];
    float xs4[2][4];
#pragma unroll
    for (int mg = 0; mg < 2; ++mg) {
        const float* xr = x + (r0 + mg * 16 + c) * NDIM;
        float sqs = 0.f;
#pragma unroll
        for (int kc = 0; kc < 2; ++kc) {
            f32x4 v0 = *(const f32x4*)(xr + kc * 32 + g * 8);
            f32x4 v1 = *(const f32x4*)(xr + kc * 32 + g * 8 + 4);
            sqs += v0[0]*v0[0] + v0[1]*v0[1] + v0[2]*v0[2] + v0[3]*v0[3];
            sqs += v1[0]*v1[0] + v1[1]*v1[1] + v1[2]*v1[2] + v1[3]*v1[3];
            bf16x8 f;
            f[0]=f2bf_n(v0[0]); f[1]=f2bf_n(v0[1]); f[2]=f2bf_n(v0[2]); f[3]=f2bf_n(v0[3]);
            f[4]=f2bf_n(v1[0]); f[5]=f2bf_n(v1[1]); f[6]=f2bf_n(v1[2]); f[7]=f2bf_n(v1[3]);
            A[mg][kc] = f;
        }
        sqs += __shfl_xor(sqs, 16);   // combine the 4 g-chunks of row (mg, c)
        sqs += __shfl_xor(sqs, 32);
#pragma unroll
        for (int rr = 0; rr < 4; ++rr)
            xs4[mg][rr] = __shfl(sqs, 4 * g + rr);   // xsq of C-layout row 4g+rr
    }

    // ---- prefetch helpers (named ping-pong sets; all loads independent) ----
    f32x2 cfA0, cfA1, cfB0, cfB1;
    bf16x8 bA00, bA01, bA10, bA11, bB00, bB01, bB10, bB11;
    bf16x8 wfA, wfB;

#define LOAD_CHUNK(ks_, cf0_, cf1_, b00_, b01_, b10_, b11_, wf_)                  \
    do {                                                                          \
        const int nt0_ = 2 * (ks_), nt1_ = 2 * (ks_) + 1;                         \
        cf0_ = *(const f32x2*)(cofp + (nt0_ * 16 + c) * 8);                       \
        cf1_ = *(const f32x2*)(cofp + (nt1_ * 16 + c) * 8);                       \
        b00_ = cfrag[(nt0_ * 2 + 0) * 64 + lane];                                 \
        b01_ = cfrag[(nt0_ * 2 + 1) * 64 + lane];                                 \
        b10_ = cfrag[(nt1_ * 2 + 0) * 64 + lane];                                 \
        b11_ = cfrag[(nt1_ * 2 + 1) * 64 + lane];                                 \
        wf_  = wfrag[(ks_) * 64 + lane];                                          \
    } while (0)

    f32x4 acc2[2] = {{0.f,0.f,0.f,0.f},{0.f,0.f,0.f,0.f}};

#define COMPUTE_CHUNK(ks_, cf0_, cf1_, b00_, b01_, b10_, b11_, wf_)               \
    do {                                                                          \
        /* t = 0 */                                                               \
        {                                                                         \
            const float a_ = cf0_[0], nb_ = cf0_[1];                              \
            const float A2_ = a_ + a_;                                            \
            _Pragma("unroll")                                                     \
            for (int mg = 0; mg < 2; ++mg) {                                      \
                f32x4 z_ = {0.f, 0.f, 0.f, 0.f};                                  \
                f32x4 acc_ = __builtin_amdgcn_mfma_f32_16x16x32_bf16(A[mg][0], b00_, z_, 0, 0, 0); \
                acc_ = __builtin_amdgcn_mfma_f32_16x16x32_bf16(A[mg][1], b01_, acc_, 0, 0, 0);     \
                _Pragma("unroll")                                                 \
                for (int rr = 0; rr < 4; ++rr) {                                  \
                    float nbx_ = fmaf(-a_, xs4[mg][rr], nb_);                     \
                    float arg_ = fmaf(A2_, acc_[rr], nbx_);                       \
                    hidb[w][(ks_) & 1][mg * 16 + 4 * g + rr][c] = f2bf_n(EXP2F(arg_)); \
                }                                                                 \
            }                                                                     \
        }                                                                         \
        /* t = 1 */                                                               \
        {                                                                         \
            const float a_ = cf1_[0], nb_ = cf1_[1];                              \
            const float A2_ = a_ + a_;                                            \
            _Pragma("unroll")                                                     \
            for (int mg = 0; mg < 2; ++mg) {                                      \
                f32x4 z_ = {0.f, 0.f, 0.f, 0.f};                                  \
                f32x4 acc_ = __builtin_amdgcn_mfma_f32_16x16x32_bf16(A[mg][0], b10_, z_, 0, 0, 0); \
                acc_ = __builtin_amdgcn_mfma_f32_16x16x32_bf16(A[mg][1], b11_, acc_, 0, 0, 0);     \
                _Pragma("unroll")                                                 \
                for (int rr = 0; rr < 4; ++rr) {                                  \
                    float nbx_ = fmaf(-a_, xs4[mg][rr], nb_);                     \
                    float arg_ = fmaf(A2_, acc_[rr], nbx_);                       \
                    hidb[w][(ks_) & 1][mg * 16 + 4 * g + rr][16 + c] = f2bf_n(EXP2F(arg_)); \
                }                                                                 \
            }                                                                     \
        }                                                                         \
        /* GEMM2 for this 32-h chunk */                                           \
        {                                                                         \
            const bf16x8 a20_ = *(const bf16x8*)&hidb[w][(ks_) & 1][c][g * 8];    \
            const bf16x8 a21_ = *(const bf16x8*)&hidb[w][(ks_) & 1][c + 16][g * 8]; \
            acc2[0] = __builtin_amdgcn_mfma_f32_16x16x32_bf16(a20_, wf_, acc2[0], 0, 0, 0); \
            acc2[1] = __builtin_amdgcn_mfma_f32_16x16x32_bf16(a21_, wf_, acc2[1], 0, 0, 0); \
        }                                                                         \
    } while (0)

    // ---- software-pipelined main loop: zero barriers ----
    LOAD_CHUNK(0, cfA0, cfA1, bA00, bA01, bA10, bA11, wfA);
#pragma unroll
    for (int ks = 0; ks < 16; ks += 2) {
        LOAD_CHUNK(ks + 1, cfB0, cfB1, bB00, bB01, bB10, bB11, wfB);
        COMPUTE_CHUNK(ks, cfA0, cfA1, bA00, bA01, bA10, bA11, wfA);
        if (ks + 2 < 16)
            LOAD_CHUNK(ks + 2, cfA0, cfA1, bA00, bA01, bA10, bA11, wfA);
        COMPUTE_CHUNK(ks + 1, cfB0, cfB1, bB00, bB01, bB10, bB11, wfB);
    }

    // ---- epilogue in registers: bias, row-sum over o (c-lanes), normalize ----
    const float bv = bias[c];
#pragma unroll
    for (int mg = 0; mg < 2; ++mg) {
        f32x4 v, s;
#pragma unroll
        for (int rr = 0; rr < 4; ++rr) { v[rr] = acc2[mg][rr] + bv; s[rr] = v[rr]; }
#pragma unroll
        for (int off = 1; off <= 8; off <<= 1) {
#pragma unroll
            for (int rr = 0; rr < 4; ++rr) s[rr] += __shfl_xor(s[rr], off);
        }
#pragma unroll
        for (int rr = 0; rr < 4; ++rr)
            out[(r0 + mg * 16 + 4 * g + rr) * NOUT + c] = v[rr] / s[rr];
    }
}

extern "C" void kernel_launch(void* const* d_in, const int* in_sizes, int n_in,
                              void* d_out, int out_size, void* d_ws, size_t ws_size,
                              hipStream_t stream) {
    const float* x    = (const float*)d_in[0];
    const float* cen  = (const float*)d_in[1];
    const float* sig  = (const float*)d_in[2];
    const float* wgt  = (const float*)d_in[3];
    const float* bias = (const float*)d_in[4];
    float* out = (float*)d_out;
    (void)in_sizes; (void)n_in; (void)ws_size; (void)out_size;

    char* ws = (char*)d_ws;
    rbf_prep<<<dim3(NHID + 16), dim3(64), 0, stream>>>(cen, sig, wgt, ws);
    rbf_main<<<dim3(1024), dim3(256), 0, stream>>>(x, bias, ws, out);
}